// Round 1
// baseline (70.716 us; speedup 1.0000x reference)
//
#include <hip/hip_runtime.h>
#include <math.h>

#define MAX_SHIFT 128
#define S_TOTAL   257
#define SGB       9          // shifts per sg-group: s in [8*sg, 8*sg+8] (overlap by 1)
#define NSG       32         // 32 shift-groups cover s=0..256
#define VY        8          // consecutive t-elements per thread per iter
#define BLK1      256        // 4 waves per K1 block
#define NW1       (BLK1/64)
#define CCH       8          // t-chunks: 32768/8 = 4096 elems per chunk, 2 iters/thread

// Theory of this version: the timed region = fixed ~40us 256MiB poison fill
// + the kernel. Old kernel (~26us) was latency-bound: 4 waves/SIMD, 4-trip
// load->wait->compute loop, cold caches each replay. This version splits work
// into (32 sg, 8 bc, 8 chunks) = 2048 blocks x 256 thr = 8192 waves (machine
// capacity) with launch_bounds forcing VGPR<=64 -> 8 waves/SIMD, so HBM/L2
// latency is hidden by TLP. Moments (Sx,Sxx,Sy,Syy) are computed only by the
// d0==0 (sg==16) blocks instead of redundantly by all 32 groups.
//
// ws layout (floats):
//   cross[sg][bc][ch][j] at ((sg*BC+bc)*CCH+ch)*SGB + j      (32*8*8*9 = 18432)
//   mom  [bc][ch][q]     at MOMBASE + (bc*CCH+ch)*4 + q       (8*8*4   = 256)
// Every slot K2 reads is written exactly once by K1 (workspace arrives poisoned).

__global__ __launch_bounds__(BLK1, 8) void spc_partial(const float* __restrict__ x,
                                                       const float* __restrict__ y,
                                                       float* __restrict__ ws,
                                                       int T, int BC) {
    const int sg  = blockIdx.x;
    const int bc  = blockIdx.y;
    const int ch  = blockIdx.z;
    const int d0  = sg * 8 - MAX_SHIFT;     // multiple of 8 -> 16B-aligned windows
    const int tid = threadIdx.x;
    const float* xb = x + (size_t)bc * T;
    const float* yb = y + (size_t)bc * T;
    const int chunk = T / CCH;              // 4096
    const int t0 = ch * chunk;
    const bool domom = (d0 == 0);           // uniform per block -> loop-unswitched

    float acc[SGB];
#pragma unroll
    for (int j = 0; j < SGB; ++j) acc[j] = 0.f;
    float sx = 0.f, sxx = 0.f, sy = 0.f, syy = 0.f;

    for (int t = t0 + tid * VY; t < t0 + chunk; t += BLK1 * VY) {   // 2 trips
        float yv[VY], xw[16];               // window covers e+j in [0,16)
        *(float4*)(yv)     = *(const float4*)(yb + t);
        *(float4*)(yv + 4) = *(const float4*)(yb + t + 4);

        const int g0 = t + d0;
        if (g0 >= 0 && g0 + 16 <= T) {      // interior: 4 aligned float4 loads
#pragma unroll
            for (int i = 0; i < 4; ++i)
                *(float4*)(xw + 4 * i) = *(const float4*)(xb + g0 + 4 * i);
        } else {                            // boundary: guarded scalar loads
#pragma unroll
            for (int i = 0; i < 16; ++i) {
                int g = g0 + i;
                xw[i] = (g >= 0 && g < T) ? xb[g] : 0.f;
            }
        }

#pragma unroll
        for (int e = 0; e < VY; ++e) {
            const float yvv = yv[e];
#pragma unroll
            for (int j = 0; j < SGB; ++j)
                acc[j] = fmaf(xw[e + j], yvv, acc[j]);
            if (domom) {                    // only sg==16: xw[e] == xb[t+e]
                sy += yvv;   syy = fmaf(yvv, yvv, syy);
                sx += xw[e]; sxx = fmaf(xw[e], xw[e], sxx);
            }
        }
    }

    // ---- reduce within block, write partials ----
    __shared__ float red[SGB + 4][NW1];
    const int lane = tid & 63, wave = tid >> 6;
#pragma unroll
    for (int j = 0; j < SGB; ++j) {
        float v = acc[j];
        for (int off = 32; off; off >>= 1) v += __shfl_down(v, off, 64);
        if (lane == 0) red[j][wave] = v;
    }
    if (domom) {
        float v4[4] = {sx, sxx, sy, syy};
#pragma unroll
        for (int q = 0; q < 4; ++q) {
            float v = v4[q];
            for (int off = 32; off; off >>= 1) v += __shfl_down(v, off, 64);
            if (lane == 0) red[SGB + q][wave] = v;
        }
    }
    __syncthreads();

    if (tid < SGB) {
        float v = 0.f;
#pragma unroll
        for (int w = 0; w < NW1; ++w) v += red[tid][w];
        ws[(size_t)((sg * BC + bc) * CCH + ch) * SGB + tid] = v;
    }
    if (domom && tid >= SGB && tid < SGB + 4) {
        const int q = tid - SGB;
        float v = 0.f;
#pragma unroll
        for (int w = 0; w < NW1; ++w) v += red[SGB + q][w];
        ws[(size_t)NSG * BC * CCH * SGB + (size_t)(bc * CCH + ch) * 4 + q] = v;
    }
}

// One wave per output (s, bc): sum 8 chunk partials, edge corrections, finalize.
__global__ __launch_bounds__(64) void spc_final(const float* __restrict__ x,
                                                const float* __restrict__ ws,
                                                float* __restrict__ out,
                                                int T, int BC) {
    const int s    = blockIdx.x;            // 0..256
    const int bc   = blockIdx.y;
    const int lane = threadIdx.x;
    const int sg   = (s >= NSG * 8) ? (NSG - 1) : (s >> 3);
    const int j    = s - sg * 8;            // < SGB
    const float* xb = x + (size_t)bc * T;

    float cr = 0.f, Sx = 0.f, Sxx = 0.f, Sy = 0.f, Syy = 0.f;
    if (lane < CCH) {
        cr = ws[(size_t)((sg * BC + bc) * CCH + lane) * SGB + j];
        const float* mb = ws + (size_t)NSG * BC * CCH * SGB + (size_t)(bc * CCH + lane) * 4;
        Sx = mb[0]; Sxx = mb[1]; Sy = mb[2]; Syy = mb[3];
    }
    for (int off = 4; off; off >>= 1) {     // lanes 0..7 only feed lane 0
        cr  += __shfl_down(cr,  off, 64);
        Sx  += __shfl_down(Sx,  off, 64);
        Sxx += __shfl_down(Sxx, off, 64);
        Sy  += __shfl_down(Sy,  off, 64);
        Syy += __shfl_down(Syy, off, 64);
    }

    // edge sums for shift s: window drops prefix (d>0) or suffix (d<0) of x
    const int d = s - MAX_SHIFT;
    float pw = 0.f, pw2 = 0.f;
    if (d > 0) {
        for (int i = lane; i < d; i += 64)  { float v = xb[i];         pw += v; pw2 = fmaf(v, v, pw2); }
    } else if (d < 0) {
        for (int i = lane; i < -d; i += 64) { float v = xb[T + d + i]; pw += v; pw2 = fmaf(v, v, pw2); }
    }
    for (int off = 32; off; off >>= 1) {
        pw  += __shfl_down(pw,  off, 64);
        pw2 += __shfl_down(pw2, off, 64);
    }

    if (lane == 0) {
        const float Sw   = Sx  - pw;
        const float Sw2  = Sxx - pw2;
        const float invT = 1.0f / (float)T;
        const float corr  = cr  - Sw * Sy * invT;
        const float normx = Sw2 - Sw * Sw * invT;
        const float normy = Syy - Sy * Sy * invT;
        out[(size_t)s * BC + bc] = corr / sqrtf(normx * normy);
    }
}

extern "C" void kernel_launch(void* const* d_in, const int* in_sizes, int n_in,
                              void* d_out, int out_size, void* d_ws, size_t ws_size,
                              hipStream_t stream) {
    const float* x = (const float*)d_in[0];
    const float* y = (const float*)d_in[1];
    float* out = (float*)d_out;
    float* ws  = (float*)d_ws;

    const int BC = out_size / S_TOTAL;      // 8
    const int T  = in_sizes[0] / BC;        // 32768

    dim3 g1(NSG, BC, CCH);                  // 2048 blocks x 256 thr = 8192 waves
    spc_partial<<<g1, BLK1, 0, stream>>>(x, y, ws, T, BC);

    dim3 g2(S_TOTAL, BC);                   // 2056 one-wave finalize blocks
    spc_final<<<g2, 64, 0, stream>>>(x, ws, out, T, BC);
}

// Round 2
// 65.542 us; speedup vs baseline: 1.0789x; 1.0789x over previous
//
#include <hip/hip_runtime.h>
#include <math.h>

#define MAX_SHIFT 128
#define S_TOTAL   257
#define SGB       9                    // shifts computed per block: s = 8*sg .. 8*sg+8
#define NSG       32                   // 32 shift-groups cover s = 0..256
#define VY        16                   // consecutive t-elements per thread per iter
#define BLOCK     1024                 // 16 waves = 4 waves/SIMD, 1 block/CU
#define NW        (BLOCK / 64)
#define NQ        (SGB + 4)            // 9 cross + W, W2, Sy, Syy
#define WIN       (VY + 8)             // 24-float x window per thread-iter

// Single dispatch (round 1 showed each extra launch costs ~5us).
// Key change vs round 0: XCD-aware bc mapping. Old grid (32 sg, 8 bc) round-
// robins linear ids across XCDs so every XCD touched all 8 bc = 4 MB = exactly
// its 4 MiB L2 -> the 32x re-read of x/y per bc thrashed to HBM (occupancy-
// invariant, which is why round 1's 2x-occupancy split was a wash). Now
// bc = id & 7: with id%8 -> XCD round-robin, each XCD serves ONE bc (256 KB
// working set), x/y are HBM-fetched once and all shift-group re-reads L2-hit.
// Also: no separate full-range x loads -- window sums W = sum(xw), W2 = sum(xw^2)
// are corrected per shift by an 8-element edge sum (every block's shift range
// lies entirely on one side of d=0, so a single branch per block suffices).
__global__ __launch_bounds__(BLOCK) void spc_kernel(const float* __restrict__ x,
                                                    const float* __restrict__ y,
                                                    float* __restrict__ out,
                                                    int T, int BC) {
    const int bc  = blockIdx.x & 7;        // one bc per XCD (id % 8 round-robin)
    const int sg  = blockIdx.x >> 3;       // shift group 0..31
    const int s0  = sg * 8;
    const int d0  = s0 - MAX_SHIFT;        // multiple of 8 -> 32B-aligned windows
    const int tid = threadIdx.x;
    const float* xb = x + (size_t)bc * T;
    const float* yb = y + (size_t)bc * T;

    float acc[SGB];
#pragma unroll
    for (int j = 0; j < SGB; ++j) acc[j] = 0.f;
    float w = 0.f, w2 = 0.f, sy = 0.f, syy = 0.f;

    // main loop: 2 trips of 16 t-elements per thread
    for (int t = tid * VY; t < T; t += BLOCK * VY) {
        float yv[VY], xw[WIN];             // window covers e+j for e<16, j<9
#pragma unroll
        for (int i = 0; i < VY / 4; ++i)
            *(float4*)(yv + 4 * i) = *(const float4*)(yb + t + 4 * i);

        const int g0 = t + d0;
        if (g0 >= 0 && g0 + WIN <= T) {    // interior: 6 aligned float4 loads
#pragma unroll
            for (int i = 0; i < WIN / 4; ++i)
                *(float4*)(xw + 4 * i) = *(const float4*)(xb + g0 + 4 * i);
        } else {                           // boundary: guarded scalar loads (zero-pad)
#pragma unroll
            for (int i = 0; i < WIN; ++i) {
                int g = g0 + i;
                xw[i] = (g >= 0 && g < T) ? xb[g] : 0.f;
            }
        }

#pragma unroll
        for (int e = 0; e < VY; ++e) {
            const float yvv = yv[e];
#pragma unroll
            for (int j = 0; j < SGB; ++j)
                acc[j] = fmaf(xw[e + j], yvv, acc[j]);   // compile-time indices
            sy += yvv;   syy = fmaf(yvv, yvv, syy);
            w  += xw[e]; w2  = fmaf(xw[e], xw[e], w2);   // window sums (shift j=0)
        }
    }

    // ---- wave-level reductions of the 13 partials ----
    __shared__ float red[NQ][NW];
    __shared__ float tot[NQ];
    const int lane = tid & 63, wave = tid >> 6;
#pragma unroll
    for (int j = 0; j < SGB; ++j) {
        float v = acc[j];
        for (int off = 32; off; off >>= 1) v += __shfl_down(v, off, 64);
        if (lane == 0) red[j][wave] = v;
    }
    {
        float v4[4] = {w, w2, sy, syy};
#pragma unroll
        for (int q = 0; q < 4; ++q) {
            float v = v4[q];
            for (int off = 32; off; off >>= 1) v += __shfl_down(v, off, 64);
            if (lane == 0) red[SGB + q][wave] = v;
        }
    }
    __syncthreads();

    if (tid < NQ) {
        float v = 0.f;
#pragma unroll
        for (int wv = 0; wv < NW; ++wv) v += red[tid][wv];
        tot[tid] = v;
    }
    __syncthreads();

    // ---- finalize: blocks write j=0..7; sg==31 also writes j=8 (s=256) ----
    if (tid < SGB && (tid < 8 || sg == NSG - 1)) {
        const int s = s0 + tid;
        // edge correction: Sw(shift j) differs from W by <=8 elements at one end
        float ev[8];
        const float* bp = xb + ((d0 >= 0) ? d0 : T + d0);   // 32B-aligned
        *(float4*)(ev)     = *(const float4*)(bp);
        *(float4*)(ev + 4) = *(const float4*)(bp + 4);
        float es = 0.f, es2 = 0.f;
#pragma unroll
        for (int i = 0; i < 8; ++i)
            if (i < tid) { es += ev[i]; es2 = fmaf(ev[i], ev[i], es2); }

        const float W   = tot[SGB + 0];
        const float W2  = tot[SGB + 1];
        const float Sy  = tot[SGB + 2];
        const float Syy = tot[SGB + 3];
        const float Sw  = (d0 >= 0) ? (W  - es)  : (W  + es);
        const float Sw2 = (d0 >= 0) ? (W2 - es2) : (W2 + es2);

        const float invT  = 1.0f / (float)T;
        const float cr    = tot[tid];
        const float corr  = cr  - Sw * Sy * invT;
        const float normx = Sw2 - Sw * Sw * invT;
        const float normy = Syy - Sy * Sy * invT;
        out[(size_t)s * BC + bc] = corr / sqrtf(normx * normy);
    }
}

extern "C" void kernel_launch(void* const* d_in, const int* in_sizes, int n_in,
                              void* d_out, int out_size, void* d_ws, size_t ws_size,
                              hipStream_t stream) {
    const float* x = (const float*)d_in[0];
    const float* y = (const float*)d_in[1];
    float* out = (float*)d_out;

    const int BC = out_size / S_TOTAL;   // 8
    const int T  = in_sizes[0] / BC;     // 32768

    spc_kernel<<<dim3(NSG * BC), BLOCK, 0, stream>>>(x, y, out, T, BC);
}